// Round 9
// baseline (306.117 us; speedup 1.0000x reference)
//
#include <hip/hip_runtime.h>
#include <hip/hip_bf16.h>
#include <hip/hip_fp8.h>

// ---------- helpers ----------
__device__ __forceinline__ float b2f(unsigned short u) {
  return __uint_as_float(((unsigned int)u) << 16);
}
__device__ __forceinline__ unsigned short f2b(float f) {
  unsigned int x = __float_as_uint(f);
  unsigned int r = x + 0x7FFFu + ((x >> 16) & 1u);  // RNE
  return (unsigned short)(r >> 16);
}
__device__ __forceinline__ unsigned int pack2(float lo, float hi) {
  return (unsigned int)f2b(lo) | ((unsigned int)f2b(hi) << 16);
}
// accumulate 8 bf16 (one uint4) into a[0..7]; even idx = low half, odd = high.
__device__ __forceinline__ void acc8(float* a, uint4 p) {
  a[0] += __uint_as_float(p.x << 16); a[1] += __uint_as_float(p.x & 0xFFFF0000u);
  a[2] += __uint_as_float(p.y << 16); a[3] += __uint_as_float(p.y & 0xFFFF0000u);
  a[4] += __uint_as_float(p.z << 16); a[5] += __uint_as_float(p.z & 0xFFFF0000u);
  a[6] += __uint_as_float(p.w << 16); a[7] += __uint_as_float(p.w & 0xFFFF0000u);
}
// fp8 e4m3 (OCP) scalar encode via HIP type (HW cvt on gfx950)
__device__ __forceinline__ unsigned char f2fp8(float f) {
  __hip_fp8_e4m3 q(f);
  return (unsigned char)q.__x;
}

typedef short bf16x8 __attribute__((ext_vector_type(8)));  // 8 bf16 = 4 VGPRs
typedef float f32x4 __attribute__((ext_vector_type(4)));
typedef float f32x2 __attribute__((ext_vector_type(2)));

// HW packed fp8 decode + packed f32 accumulate: 8 features = 4 cvt_pk + 4 pk_add.
__device__ __forceinline__ void acc8fp8(f32x2* a, uint2 p) {
  a[0] += __builtin_amdgcn_cvt_pk_f32_fp8(p.x, false);
  a[1] += __builtin_amdgcn_cvt_pk_f32_fp8(p.x, true);
  a[2] += __builtin_amdgcn_cvt_pk_f32_fp8(p.y, false);
  a[3] += __builtin_amdgcn_cvt_pk_f32_fp8(p.y, true);
}

#define CHUNK 8192          // edges per P1/P3 block
#define NBUCKP 1024         // padded bucket count (bucket = dst >> 7, N <= 131072)
#define RSTRIDE 4224        // per-wave LDS region, shorts (= 8448B = 16x132 f32 stage)

// ---------- dtype detection + zero-row init ----------
__global__ void detect_kernel(const void* __restrict__ x_raw,
                              const void* __restrict__ idx_raw,
                              int* __restrict__ hdr,
                              unsigned short* __restrict__ xc_z,
                              unsigned char* __restrict__ h8_z) {
  int lane = threadIdx.x;  // 64 threads
  if (lane < 8) ((uint4*)xc_z)[lane] = (uint4){0u, 0u, 0u, 0u};
  else if (lane < 16) ((uint4*)h8_z)[lane - 8] = (uint4){0u, 0u, 0u, 0u};
  const unsigned short* xb = (const unsigned short*)x_raw;
  unsigned short u = xb[2 * lane];
  int e = (u >> 7) & 0xFF;
  bool sane = ((u & 0x7FFFu) == 0) || (e >= 107 && e <= 137);
  unsigned long long m = __ballot(sane);
  const int* ib = (const int*)idx_raw;
  int v = ib[2 * lane + 1];
  unsigned long long m2 = __ballot(v != 0);
  if (lane == 0) {
    hdr[0] = (__popcll(m) >= 32) ? 0 : 1;
    hdr[1] = (m2 == 0ull) ? 1 : 0;
  }
}

// ---------- weights -> fragment-major bf16 (Wf), biases -> f32 ----------
__global__ void reorder_w_kernel(const void* __restrict__ W1l, const void* __restrict__ W1r,
                                 const void* __restrict__ W2l, const void* __restrict__ W2r,
                                 const void* __restrict__ b1, const void* __restrict__ b2,
                                 const int* __restrict__ hdr,
                                 unsigned short* __restrict__ Wf1, unsigned short* __restrict__ Wf2,
                                 float* __restrict__ b1_f, float* __restrict__ b2_f) {
  int i = blockIdx.x * blockDim.x + threadIdx.x;
  const bool f32in = hdr[0] != 0;
  if (i < 6144) {
    const void* Wl; const void* Wr; int K; unsigned short* dst; int j;
    if (i < 2048) { Wl = W1l; Wr = W1r; K = 64;  dst = Wf1; j = i; }
    else          { Wl = W2l; Wr = W2r; K = 128; dst = Wf2; j = i - 2048; }
    int c = j >> 9, ji = (j >> 6) & 7, lane = j & 63;
    int quad = lane >> 4, m16 = lane & 15;
    int kb = c * 32;
    const void* W = (kb < K) ? Wl : Wr;
    if (kb >= K) kb -= K;
    int row = ji * 16 + m16;
    size_t src = (size_t)row * K + kb + quad * 8;
    unsigned short out[8];
    #pragma unroll
    for (int t = 0; t < 8; ++t) {
      float v = f32in ? ((const float*)W)[src + t] : b2f(((const unsigned short*)W)[src + t]);
      out[t] = f2b(v);
    }
    *(uint4*)(dst + (size_t)j * 8) = *(const uint4*)out;
  } else if (i < 6272) {
    int o = i - 6144;
    b1_f[o] = f32in ? ((const float*)b1)[o] : b2f(((const unsigned short*)b1)[o]);
  } else if (i < 6400) {
    int o = i - 6272;
    b2_f[o] = f32in ? ((const float*)b2)[o] : b2f(((const unsigned short*)b2)[o]);
  }
}

// ---------- x -> bf16: row-major copy (gather source) + tiled copy (gemm1 A2) ----------
__global__ void convert_x_kernel(const void* __restrict__ x_raw,
                                 const int* __restrict__ hdr,
                                 unsigned short* __restrict__ xc,
                                 unsigned short* __restrict__ xc_til, int n_elems) {
  int i = blockIdx.x * blockDim.x + threadIdx.x;
  if (i >= n_elems) return;
  unsigned short v = hdr[0] ? f2b(((const float*)x_raw)[i]) : ((const unsigned short*)x_raw)[i];
  xc[i] = v;
  int n = i >> 6, f = i & 63;
  xc_til[((size_t)(n >> 4) * 8 + (f >> 3)) * 128 + (n & 15) * 8 + (f & 7)] = v;
}

// ---------- P1: per-chunk bucket histogram ----------
__global__ __launch_bounds__(256) void hist_chunks_kernel(
    const int* __restrict__ idx_raw, const int* __restrict__ hdr,
    int* __restrict__ H, int n_edges, int NC) {
  __shared__ int h[NBUCKP];
  for (int i = threadIdx.x; i < NBUCKP; i += 256) h[i] = 0;
  __syncthreads();
  const int c = blockIdx.x;
  const int base = c * CHUNK;
  const int lim = min(n_edges - base, CHUNK);
  if (hdr[1]) {
    const uint4* dp = (const uint4*)(idx_raw + 2 * (size_t)n_edges + 2 * (size_t)base);
    #pragma unroll
    for (int t = 0; t < CHUNK / 512; ++t) {
      int q = t * 256 + threadIdx.x;
      int e = 2 * q;
      if (e < lim) {
        uint4 v = dp[q];
        atomicAdd(&h[((int)v.x) >> 7], 1);
        if (e + 1 < lim) atomicAdd(&h[((int)v.z) >> 7], 1);
      }
    }
  } else {
    const uint4* dp = (const uint4*)(idx_raw + (size_t)n_edges + base);
    #pragma unroll
    for (int t = 0; t < CHUNK / 1024; ++t) {
      int q = t * 256 + threadIdx.x;
      int e = 4 * q;
      if (e < lim) {
        uint4 v = dp[q];
        atomicAdd(&h[((int)v.x) >> 7], 1);
        if (e + 1 < lim) atomicAdd(&h[((int)v.y) >> 7], 1);
        if (e + 2 < lim) atomicAdd(&h[((int)v.z) >> 7], 1);
        if (e + 3 < lim) atomicAdd(&h[((int)v.w) >> 7], 1);
      }
    }
  }
  __syncthreads();
  for (int i = threadIdx.x; i < NBUCKP; i += 256) H[(size_t)i * NC + c] = h[i];
}

// ---------- P2: flat exclusive scan ----------
__global__ __launch_bounds__(256) void gscan_sums_kernel(const int* __restrict__ arr,
                                                         int* __restrict__ blockSums, int n) {
  __shared__ int ws[4];
  int tid = threadIdx.x, lane = tid & 63, wid = tid >> 6;
  int base = blockIdx.x * 2048 + tid * 8;
  int s = 0;
  #pragma unroll
  for (int t = 0; t < 8; ++t) {
    int i = base + t;
    if (i < n) s += arr[i];
  }
  #pragma unroll
  for (int m = 1; m < 64; m <<= 1) s += __shfl_xor(s, m, 64);
  if (lane == 0) ws[wid] = s;
  __syncthreads();
  if (tid == 0) blockSums[blockIdx.x] = ws[0] + ws[1] + ws[2] + ws[3];
}

__global__ void gscan_offsets_kernel(const int* __restrict__ blockSums,
                                     int* __restrict__ blockOffs, int nb) {
  int lane = threadIdx.x;  // 64
  int carry = 0;
  for (int start = 0; start < nb; start += 64) {
    int i = start + lane;
    int v = (i < nb) ? blockSums[i] : 0;
    int isc = v;
    #pragma unroll
    for (int off = 1; off < 64; off <<= 1) {
      int t = __shfl_up(isc, off, 64);
      if (lane >= off) isc += t;
    }
    if (i < nb) blockOffs[i] = carry + isc - v;
    carry += __shfl(isc, 63, 64);
  }
}

__global__ __launch_bounds__(256) void gscan_emit_kernel(const int* __restrict__ arr,
                                                         const int* __restrict__ blockOffs,
                                                         int* __restrict__ out, int n) {
  __shared__ int ws[4];
  int tid = threadIdx.x, lane = tid & 63, wid = tid >> 6;
  int base = blockIdx.x * 2048 + tid * 8;
  int v[8];
  int s = 0;
  #pragma unroll
  for (int t = 0; t < 8; ++t) {
    int i = base + t;
    v[t] = (i < n) ? arr[i] : 0;
    s += v[t];
  }
  int isc = s;
  #pragma unroll
  for (int off = 1; off < 64; off <<= 1) {
    int t = __shfl_up(isc, off, 64);
    if (lane >= off) isc += t;
  }
  if (lane == 63) ws[wid] = isc;
  __syncthreads();
  int wb = 0;
  #pragma unroll
  for (int w = 0; w < 4; ++w)
    if (w < wid) wb += ws[w];
  int excl = blockOffs[blockIdx.x] + wb + isc - s;
  #pragma unroll
  for (int t = 0; t < 8; ++t) {
    int i = base + t;
    if (i < n) {
      out[i] = excl;
      excl += v[t];
    }
  }
}

// ---------- P3: scatter into bucket-sorted ebuf ----------
__global__ __launch_bounds__(256) void scatter_kernel(
    const int* __restrict__ idx_raw, const int* __restrict__ hdr,
    const int* __restrict__ O, unsigned long long* __restrict__ ebuf,
    int n_edges, int NC) {
  __shared__ int base[NBUCKP];
  const int c = blockIdx.x;
  for (int i = threadIdx.x; i < NBUCKP; i += 256) base[i] = O[(size_t)i * NC + c];
  __syncthreads();
  const int eb = c * CHUNK;
  const int lim = min(n_edges - eb, CHUNK);
  if (hdr[1]) {
    const uint4* sp = (const uint4*)(idx_raw + 2 * (size_t)eb);
    const uint4* dp = (const uint4*)(idx_raw + 2 * (size_t)n_edges + 2 * (size_t)eb);
    #pragma unroll
    for (int t = 0; t < CHUNK / 512; ++t) {
      int q = t * 256 + threadIdx.x;
      int e = 2 * q;
      if (e < lim) {
        uint4 sv = sp[q], dv = dp[q];
        int p0 = atomicAdd(&base[((int)dv.x) >> 7], 1);
        ebuf[p0] = (unsigned long long)sv.x | ((unsigned long long)dv.x << 32);
        if (e + 1 < lim) {
          int p1 = atomicAdd(&base[((int)dv.z) >> 7], 1);
          ebuf[p1] = (unsigned long long)sv.z | ((unsigned long long)dv.z << 32);
        }
      }
    }
  } else {
    const uint4* sp = (const uint4*)(idx_raw + (size_t)eb);
    const uint4* dp = (const uint4*)(idx_raw + (size_t)n_edges + eb);
    #pragma unroll
    for (int t = 0; t < CHUNK / 1024; ++t) {
      int q = t * 256 + threadIdx.x;
      int e = 4 * q;
      if (e < lim) {
        uint4 sv = sp[q], dv = dp[q];
        int p0 = atomicAdd(&base[((int)dv.x) >> 7], 1);
        ebuf[p0] = (unsigned long long)sv.x | ((unsigned long long)dv.x << 32);
        if (e + 1 < lim) {
          int p1 = atomicAdd(&base[((int)dv.y) >> 7], 1);
          ebuf[p1] = (unsigned long long)sv.y | ((unsigned long long)dv.y << 32);
        }
        if (e + 2 < lim) {
          int p2 = atomicAdd(&base[((int)dv.z) >> 7], 1);
          ebuf[p2] = (unsigned long long)sv.z | ((unsigned long long)dv.z << 32);
        }
        if (e + 3 < lim) {
          int p3 = atomicAdd(&base[((int)dv.w) >> 7], 1);
          ebuf[p3] = (unsigned long long)sv.w | ((unsigned long long)dv.w << 32);
        }
      }
    }
  }
}

// ---------- P4: per-bucket CSR finalize ----------
__global__ __launch_bounds__(256) void bucket_csr_kernel(
    const unsigned long long* __restrict__ ebuf, const int* __restrict__ O,
    int* __restrict__ col, int* __restrict__ row_start, float* __restrict__ deg_inv,
    int n_nodes, int n_edges, int NC) {
  __shared__ int cntl[128];
  __shared__ int cur[128];
  __shared__ int w0tot;
  const int b = blockIdx.x, tid = threadIdx.x;
  const int node0 = b << 7;
  const int beg = O[(size_t)b * NC];
  const int end = (b + 1 < NBUCKP) ? O[(size_t)(b + 1) * NC] : n_edges;
  if (tid < 128) cntl[tid] = 0;
  __syncthreads();
  for (int e = beg + tid; e < end; e += 256) {
    int d = (int)(ebuf[e] >> 32);
    atomicAdd(&cntl[d - node0], 1);
  }
  __syncthreads();
  int v = (tid < 128) ? cntl[tid] : 0;
  int lane = tid & 63;
  int isc = v;
  #pragma unroll
  for (int o = 1; o < 64; o <<= 1) {
    int t = __shfl_up(isc, o, 64);
    if (lane >= o) isc += t;
  }
  if (tid == 63) w0tot = isc;
  __syncthreads();
  int incl = isc + ((tid >= 64 && tid < 128) ? w0tot : 0);
  int excl = incl - v;
  if (tid < 128) {
    cur[tid] = excl;
    int node = node0 + tid;
    if (node < n_nodes) {
      row_start[node] = beg + excl;
      deg_inv[node] = 1.0f / (float)((v > 1) ? v : 1);
    }
  }
  __syncthreads();
  for (int e = beg + tid; e < end; e += 256) {
    unsigned long long u = ebuf[e];
    int s = (int)(u & 0xFFFFFFFFull);
    int d = (int)(u >> 32);
    int r = atomicAdd(&cur[d - node0], 1);  // LDS atomic
    col[beg + r] = s;
  }
  if (b == 0 && tid == 0) row_start[n_nodes] = n_edges;
}

// ============================================================================
// Fused gather+GEMM. Block = 128 nodes, 4 waves x 32 nodes. Per-wave LDS
// region (RSTRIDE shorts, chunk-padded to 132 shorts -> <=2-way banks) holds:
//   phase 1: the wave's gathered A1 tile in MFMA fragment order
//   phase 3: the f32 epilogue stage (regions alias; A1 ds_reads complete
//            before stage writes -- same wave, in-order; regions wave-private
//            so NO barriers anywhere).
// Chunk c, slot s of tile t lives at short-offset (t*K8 + c)*132 + s*8.
// ============================================================================

// ---------- fused layer 1: gather(xc) -> [agg|xc_til] @ Wf1 -> relu -> C8+Ctil ----------
__global__ __launch_bounds__(256, 4) void fused1_kernel(
    const unsigned short* __restrict__ xc, const int* __restrict__ row_start,
    const int* __restrict__ col, const float* __restrict__ deg_inv,
    const unsigned short* __restrict__ A2,  // xc_til
    const unsigned short* __restrict__ Wf, const float* __restrict__ bias,
    unsigned char* __restrict__ C8, unsigned short* __restrict__ Ctil,
    int n_nodes) {
  __shared__ unsigned short smem[4 * RSTRIDE];
  const int tid = threadIdx.x;
  const int wave = tid >> 6, lane = tid & 63;
  unsigned short* wls = smem + wave * RSTRIDE;
  const int m16 = lane & 15, quad = lane >> 4;
  const int nb = blockIdx.x * 128 + wave * 32;

  // ---- gather phase: 2 nodes per iteration (32-lane halves), 16 iters ----
  {
    int l32 = lane & 31;
    int rg = l32 >> 3, fq = l32 & 7;
    for (int it = 0; it < 16; ++it) {
      int ln = 2 * it + (lane >> 5);
      int n = nb + ln;
      if (n < n_nodes) {
        int beg = row_start[n], end = row_start[n + 1];
        float a[8];
        #pragma unroll
        for (int t = 0; t < 8; ++t) a[t] = 0.f;
        for (int blk = beg; blk < end; blk += 32) {
          int ce = blk + l32;
          int cc = col[ce < end ? ce : end - 1];
          int cl = (ce < end) ? cc : n_nodes;   // sentinel zero row
          int slv[8];
          #pragma unroll
          for (int k = 0; k < 8; ++k)
            if (blk + 4 * k < end)
              slv[k] = __shfl(cl, 4 * k + rg, 32);
          uint4 p[8];
          #pragma unroll
          for (int k = 0; k < 8; ++k)
            if (blk + 4 * k < end)
              p[k] = *(const uint4*)(xc + (size_t)slv[k] * 64 + fq * 8);
          #pragma unroll
          for (int k = 0; k < 8; ++k)
            if (blk + 4 * k < end)
              acc8(a, p[k]);
        }
        #pragma unroll
        for (int m = 8; m <= 16; m <<= 1)
          #pragma unroll
          for (int t = 0; t < 8; ++t) a[t] += __shfl_xor(a[t], m, 64);
        if (rg == 0) {
          float di = deg_inv[n];
          uint4 o;
          o.x = pack2(a[0] * di, a[1] * di);
          o.y = pack2(a[2] * di, a[3] * di);
          o.z = pack2(a[4] * di, a[5] * di);
          o.w = pack2(a[6] * di, a[7] * di);
          *(uint4*)(wls + ((ln >> 4) * 8 + fq) * 132 + (ln & 15) * 8) = o;
        }
      }
    }
  }

  // ---- MFMA phase: [A1(LDS) | A2(xc_til)] @ Wf1 ----
  f32x4 acc[2][8];
  #pragma unroll
  for (int mi = 0; mi < 2; ++mi)
    #pragma unroll
    for (int ji = 0; ji < 8; ++ji) acc[mi][ji] = (f32x4){0.f, 0.f, 0.f, 0.f};

  const int t0 = nb >> 4;  // global tile index for A2
  #pragma unroll
  for (int c = 0; c < 4; ++c) {
    bf16x8 a0, a1;
    if (c < 2) {
      const unsigned short* p = wls + (c * 4 + quad) * 132 + m16 * 8;
      a0 = *(const bf16x8*)p;
      a1 = *(const bf16x8*)(p + 8 * 132);
    } else {
      const int cc = c - 2;
      const unsigned short* p = A2 + (size_t)(t0 * 8 + cc * 4) * 128 + lane * 8;
      a0 = *(const bf16x8*)p;
      a1 = *(const bf16x8*)(p + 8 * 128);
    }
    bf16x8 w[8];
    #pragma unroll
    for (int ji = 0; ji < 8; ++ji)
      w[ji] = *(const bf16x8*)(Wf + ((size_t)(c * 8 + ji) * 64 + lane) * 8);
    #pragma unroll
    for (int ji = 0; ji < 8; ++ji) {
      acc[0][ji] = __builtin_amdgcn_mfma_f32_16x16x32_bf16(a0, w[ji], acc[0][ji], 0, 0, 0);
      acc[1][ji] = __builtin_amdgcn_mfma_f32_16x16x32_bf16(a1, w[ji], acc[1][ji], 0, 0, 0);
    }
  }

  // ---- epilogue: stage in (aliased) wave-private LDS, wide stores ----
  float* S = (float*)wls;  // 16 x 132 f32 = 8448B = RSTRIDE shorts
  #pragma unroll
  for (int mi = 0; mi < 2; ++mi) {
    #pragma unroll
    for (int ji = 0; ji < 8; ++ji) {
      int j = ji * 16 + m16;
      float bj = bias[j];
      #pragma unroll
      for (int r = 0; r < 4; ++r) {
        float v = acc[mi][ji][r] + bj;
        v = fmaxf(v, 0.f);  // relu
        S[(quad * 4 + r) * 132 + j] = v;
      }
    }
    const int nbase = nb + mi * 16;
    // C8: 4 rounds; 16 lanes cover one 128B fp8 row contiguously
    #pragma unroll
    for (int rd = 0; rd < 4; ++rd) {
      int row = rd * 4 + (lane >> 4), c8 = lane & 15;
      float4 v0 = *(const float4*)&S[row * 132 + c8 * 8];
      float4 v1 = *(const float4*)&S[row * 132 + c8 * 8 + 4];
      int n = nbase + row;
      if (n < n_nodes) {
        unsigned int lo = (unsigned)f2fp8(v0.x) | ((unsigned)f2fp8(v0.y) << 8) |
                          ((unsigned)f2fp8(v0.z) << 16) | ((unsigned)f2fp8(v0.w) << 24);
        unsigned int hi = (unsigned)f2fp8(v1.x) | ((unsigned)f2fp8(v1.y) << 8) |
                          ((unsigned)f2fp8(v1.z) << 16) | ((unsigned)f2fp8(v1.w) << 24);
        *(uint2*)(C8 + (size_t)n * 128 + c8 * 8) = (uint2){lo, hi};
      }
    }
    // Ctil: 4 rounds; 16 lanes cover one 256B tiled chunk contiguously
    const int tile = nbase >> 4;
    #pragma unroll
    for (int rd = 0; rd < 4; ++rd) {
      int n16 = lane & 15, c2 = rd * 4 + (lane >> 4);
      float4 v0 = *(const float4*)&S[n16 * 132 + c2 * 8];
      float4 v1 = *(const float4*)&S[n16 * 132 + c2 * 8 + 4];
      int n = nbase + n16;
      if (n < n_nodes) {
        uint4 o;
        o.x = pack2(v0.x, v0.y); o.y = pack2(v0.z, v0.w);
        o.z = pack2(v1.x, v1.y); o.w = pack2(v1.z, v1.w);
        *(uint4*)(Ctil + ((size_t)(tile * 16 + c2)) * 128 + n16 * 8) = o;
      }
    }
  }
}

// ---------- fused layer 2: gather(hbuf8 fp8) -> [agg|hbuf_til] @ Wf2 -> out ----------
__global__ __launch_bounds__(256, 4) void fused2_kernel(
    const unsigned char* __restrict__ h8, const int* __restrict__ row_start,
    const int* __restrict__ col, const float* __restrict__ deg_inv,
    const unsigned short* __restrict__ A2,  // hbuf_til
    const unsigned short* __restrict__ Wf, const float* __restrict__ bias,
    void* __restrict__ Cf, const int* __restrict__ hdr, int n_nodes) {
  __shared__ unsigned short smem[4 * RSTRIDE];
  const int tid = threadIdx.x;
  const int wave = tid >> 6, lane = tid & 63;
  unsigned short* wls = smem + wave * RSTRIDE;
  const int m16 = lane & 15, quad = lane >> 4;
  const int nb = blockIdx.x * 128 + wave * 32;

  // ---- gather phase: 1 node per iteration, 32 iters ----
  {
    int rg = quad, fq = m16;
    for (int ln = 0; ln < 32; ++ln) {
      int n = nb + ln;
      if (n >= n_nodes) break;  // wave-uniform
      int beg = row_start[n], end = row_start[n + 1];
      f32x2 a[4];
      #pragma unroll
      for (int t = 0; t < 4; ++t) a[t] = (f32x2){0.f, 0.f};
      for (int blk = beg; blk < end; blk += 64) {
        int ce = blk + lane;
        int cc = col[ce < end ? ce : end - 1];
        int cl = (ce < end) ? cc : n_nodes;   // sentinel zero row
        int iend = min(end, blk + 64);
        for (int i = blk; i < iend; i += 32) {
          int ib = (i - blk) + rg;
          int slv[8];
          #pragma unroll
          for (int k = 0; k < 8; ++k)
            if (i + 4 * k < end)
              slv[k] = __shfl(cl, ib + 4 * k, 64);
          uint2 p[8];
          #pragma unroll
          for (int k = 0; k < 8; ++k)
            if (i + 4 * k < end)
              p[k] = *(const uint2*)(h8 + (size_t)slv[k] * 128 + (unsigned)fq * 8u);
          #pragma unroll
          for (int k = 0; k < 8; ++k)
            if (i + 4 * k < end)
              acc8fp8(a, p[k]);
        }
      }
      float af[8] = {a[0][0], a[0][1], a[1][0], a[1][1],
                     a[2][0], a[2][1], a[3][0], a[3][1]};
      #pragma unroll
      for (int m = 16; m < 64; m <<= 1)
        #pragma unroll
        for (int t = 0; t < 8; ++t) af[t] += __shfl_xor(af[t], m, 64);
      if (rg == 0) {
        float di = deg_inv[n];
        uint4 o;
        o.x = pack2(af[0] * di, af[1] * di);
        o.y = pack2(af[2] * di, af[3] * di);
        o.z = pack2(af[4] * di, af[5] * di);
        o.w = pack2(af[6] * di, af[7] * di);
        *(uint4*)(wls + ((ln >> 4) * 16 + fq) * 132 + (ln & 15) * 8) = o;
      }
    }
  }

  // ---- MFMA phase: [A1(LDS) | A2(hbuf_til)] @ Wf2 ----
  f32x4 acc[2][8];
  #pragma unroll
  for (int mi = 0; mi < 2; ++mi)
    #pragma unroll
    for (int ji = 0; ji < 8; ++ji) acc[mi][ji] = (f32x4){0.f, 0.f, 0.f, 0.f};

  const int t0 = nb >> 4;  // global tile index for A2
  #pragma unroll
  for (int c = 0; c < 8; ++c) {
    bf16x8 a0, a1;
    if (c < 4) {
      const unsigned short* p = wls + (c * 4 + quad) * 132 + m16 * 8;
      a0 = *(const bf16x8*)p;
      a1 = *(const bf16x8*)(p + 16 * 132);
    } else {
      const int cc = c - 4;
      const unsigned short* p = A2 + (size_t)(t0 * 16 + cc * 4) * 128 + lane * 8;
      a0 = *(const bf16x8*)p;
      a1 = *(const bf16x8*)(p + 16 * 128);
    }
    bf16x8 w[8];
    #pragma unroll
    for (int ji = 0; ji < 8; ++ji)
      w[ji] = *(const bf16x8*)(Wf + ((size_t)(c * 8 + ji) * 64 + lane) * 8);
    #pragma unroll
    for (int ji = 0; ji < 8; ++ji) {
      acc[0][ji] = __builtin_amdgcn_mfma_f32_16x16x32_bf16(a0, w[ji], acc[0][ji], 0, 0, 0);
      acc[1][ji] = __builtin_amdgcn_mfma_f32_16x16x32_bf16(a1, w[ji], acc[1][ji], 0, 0, 0);
    }
  }

  // ---- epilogue: stage in (aliased) wave-private LDS, wide stores ----
  float* S = (float*)wls;
  const bool f32out = (hdr[0] == 1);
  #pragma unroll
  for (int mi = 0; mi < 2; ++mi) {
    #pragma unroll
    for (int ji = 0; ji < 8; ++ji) {
      int j = ji * 16 + m16;
      float bj = bias[j];
      #pragma unroll
      for (int r = 0; r < 4; ++r)
        S[(quad * 4 + r) * 132 + j] = acc[mi][ji][r] + bj;
    }
    const int nbase = nb + mi * 16;
    #pragma unroll
    for (int rd = 0; rd < 8; ++rd) {
      int q = rd * 64 + lane;
      int row = q >> 5, col4 = q & 31;
      float4 v = *(const float4*)&S[row * 132 + col4 * 4];
      int n = nbase + row;
      if (n < n_nodes) {
        if (f32out) {
          *(float4*)((float*)Cf + (size_t)n * 128 + col4 * 4) = v;
        } else {
          uint2 o;
          o.x = pack2(v.x, v.y);
          o.y = pack2(v.z, v.w);
          *(uint2*)((unsigned short*)Cf + (size_t)n * 128 + col4 * 4) = o;
        }
      }
    }
  }
}

// ---------- launch ----------
extern "C" void kernel_launch(void* const* d_in, const int* in_sizes, int n_in,
                              void* d_out, int out_size, void* d_ws, size_t ws_size,
                              hipStream_t stream) {
  const void* x_raw  = d_in[0];
  const int* idx_raw = (const int*)d_in[1];
  const void* W1l = d_in[2];
  const void* b1  = d_in[3];
  const void* W1r = d_in[4];
  const void* W2l = d_in[5];
  const void* b2  = d_in[6];
  const void* W2r = d_in[7];
  const int N = in_sizes[0] / 64;
  const int E = in_sizes[1] / 2;
  const int NP = (N + 127) & ~127;  // padded rows for tiled buffers
  const int NC = (E + CHUNK - 1) / CHUNK;
  const int NSCAN = NBUCKP * NC;
  const int NBs = (NSCAN + 2047) / 2048;
  const int NBUCK = (N + 127) >> 7;

  char* ws = (char*)d_ws;
  size_t off = 0;
  auto alloc = [&](size_t bytes) {
    char* p = ws + off;
    off = (off + bytes + 511) & ~((size_t)511);
    return p;
  };
  int* hdr        = (int*)alloc(512);
  int* H          = (int*)alloc((size_t)NSCAN * 4);
  int* O          = (int*)alloc((size_t)NSCAN * 4);
  int* blockSums  = (int*)alloc((size_t)NBs * 4);
  int* blockOffs  = (int*)alloc((size_t)NBs * 4);
  unsigned long long* ebuf = (unsigned long long*)alloc((size_t)E * 8);
  int* col        = (int*)alloc((size_t)E * 4);
  int* row_start  = (int*)alloc(((size_t)N + 1) * 4);
  float* deg_inv  = (float*)alloc((size_t)N * 4);
  unsigned short* Wf1 = (unsigned short*)alloc(32768);
  unsigned short* Wf2 = (unsigned short*)alloc(65536);
  float* b1_f     = (float*)alloc(512);
  float* b2_f     = (float*)alloc(512);
  unsigned short* xc      = (unsigned short*)alloc(((size_t)N + 1) * 64 * 2);   // +1 sentinel row
  unsigned short* xc_til  = (unsigned short*)alloc((size_t)NP * 64 * 2);
  unsigned char*  hbuf8   = (unsigned char*)alloc(((size_t)N + 1) * 128);       // +1 sentinel row
  unsigned short* hbuf_til= (unsigned short*)alloc((size_t)NP * 128 * 2);

  detect_kernel<<<1, 64, 0, stream>>>(x_raw, idx_raw, hdr,
                                      xc + (size_t)N * 64, hbuf8 + (size_t)N * 128);
  reorder_w_kernel<<<(6400 + 255) / 256, 256, 0, stream>>>(
      W1l, W1r, W2l, W2r, b1, b2, hdr, Wf1, Wf2, b1_f, b2_f);
  convert_x_kernel<<<(N * 64 + 255) / 256, 256, 0, stream>>>(x_raw, hdr, xc, xc_til, N * 64);
  hist_chunks_kernel<<<NC, 256, 0, stream>>>(idx_raw, hdr, H, E, NC);
  gscan_sums_kernel<<<NBs, 256, 0, stream>>>(H, blockSums, NSCAN);
  gscan_offsets_kernel<<<1, 64, 0, stream>>>(blockSums, blockOffs, NBs);
  gscan_emit_kernel<<<NBs, 256, 0, stream>>>(H, blockOffs, O, NSCAN);
  scatter_kernel<<<NC, 256, 0, stream>>>(idx_raw, hdr, O, ebuf, E, NC);
  bucket_csr_kernel<<<NBUCK, 256, 0, stream>>>(ebuf, O, col, row_start, deg_inv, N, E, NC);
  fused1_kernel<<<(N + 127) / 128, 256, 0, stream>>>(
      xc, row_start, col, deg_inv, xc_til, Wf1, b1_f, hbuf8, hbuf_til, N);
  fused2_kernel<<<(N + 127) / 128, 256, 0, stream>>>(
      hbuf8, row_start, col, deg_inv, hbuf_til, Wf2, b2_f, d_out, hdr, N);
}

// Round 10
// 257.654 us; speedup vs baseline: 1.1881x; 1.1881x over previous
//
#include <hip/hip_runtime.h>
#include <hip/hip_bf16.h>
#include <hip/hip_fp8.h>

// ---------- helpers ----------
__device__ __forceinline__ float b2f(unsigned short u) {
  return __uint_as_float(((unsigned int)u) << 16);
}
__device__ __forceinline__ unsigned short f2b(float f) {
  unsigned int x = __float_as_uint(f);
  unsigned int r = x + 0x7FFFu + ((x >> 16) & 1u);  // RNE
  return (unsigned short)(r >> 16);
}
__device__ __forceinline__ unsigned int pack2(float lo, float hi) {
  return (unsigned int)f2b(lo) | ((unsigned int)f2b(hi) << 16);
}
// fp8 e4m3 (OCP) scalar encode via HIP type (HW cvt on gfx950)
__device__ __forceinline__ unsigned char f2fp8(float f) {
  __hip_fp8_e4m3 q(f);
  return (unsigned char)q.__x;
}

typedef short bf16x8 __attribute__((ext_vector_type(8)));  // 8 bf16 = 4 VGPRs
typedef float f32x4 __attribute__((ext_vector_type(4)));
typedef float f32x2 __attribute__((ext_vector_type(2)));

// HW packed fp8 decode + packed f32 accumulate: 8 features = 4 cvt_pk + 4 pk_add.
// Byte k of the row = feature k; cvt_pk(word,false) -> bytes 0,1 = (.x,.y).
__device__ __forceinline__ void acc8fp8(f32x2* a, uint2 p) {
  a[0] += __builtin_amdgcn_cvt_pk_f32_fp8(p.x, false);
  a[1] += __builtin_amdgcn_cvt_pk_f32_fp8(p.x, true);
  a[2] += __builtin_amdgcn_cvt_pk_f32_fp8(p.y, false);
  a[3] += __builtin_amdgcn_cvt_pk_f32_fp8(p.y, true);
}

#define CHUNK 8192          // edges per P1/P3 block
#define NBUCKP 1024         // padded bucket count (bucket = dst >> 7, N <= 131072)

// ---------- dtype detection + zero-row init ----------
// hdr[0]: 0 = floats are bf16, 1 = floats are f32
// hdr[1]: 0 = edge_index int32, 1 = int64
// Zeroes sentinel rows (index N) of xc8 (64B) and hbuf8 (128B): ragged gather
// tails read these rows and accumulate 0 (no predication).
__global__ void detect_kernel(const void* __restrict__ x_raw,
                              const void* __restrict__ idx_raw,
                              int* __restrict__ hdr,
                              unsigned char* __restrict__ x8_z,
                              unsigned char* __restrict__ h8_z) {
  int lane = threadIdx.x;  // 64 threads
  if (lane < 4) ((uint4*)x8_z)[lane] = (uint4){0u, 0u, 0u, 0u};
  else if (lane < 12) ((uint4*)h8_z)[lane - 4] = (uint4){0u, 0u, 0u, 0u};
  const unsigned short* xb = (const unsigned short*)x_raw;
  unsigned short u = xb[2 * lane];
  int e = (u >> 7) & 0xFF;
  bool sane = ((u & 0x7FFFu) == 0) || (e >= 107 && e <= 137);
  unsigned long long m = __ballot(sane);
  const int* ib = (const int*)idx_raw;
  int v = ib[2 * lane + 1];
  unsigned long long m2 = __ballot(v != 0);
  if (lane == 0) {
    hdr[0] = (__popcll(m) >= 32) ? 0 : 1;
    hdr[1] = (m2 == 0ull) ? 1 : 0;
  }
}

// ---------- weights -> fragment-major bf16 (Wf), biases -> f32 ----------
// Wf layout: chunk index (c*8 + ji), 64 lanes of 8 bf16 each (16B).
__global__ void reorder_w_kernel(const void* __restrict__ W1l, const void* __restrict__ W1r,
                                 const void* __restrict__ W2l, const void* __restrict__ W2r,
                                 const void* __restrict__ b1, const void* __restrict__ b2,
                                 const int* __restrict__ hdr,
                                 unsigned short* __restrict__ Wf1, unsigned short* __restrict__ Wf2,
                                 float* __restrict__ b1_f, float* __restrict__ b2_f) {
  int i = blockIdx.x * blockDim.x + threadIdx.x;
  const bool f32in = hdr[0] != 0;
  if (i < 6144) {
    const void* Wl; const void* Wr; int K; unsigned short* dst; int j;
    if (i < 2048) { Wl = W1l; Wr = W1r; K = 64;  dst = Wf1; j = i; }
    else          { Wl = W2l; Wr = W2r; K = 128; dst = Wf2; j = i - 2048; }
    int c = j >> 9, ji = (j >> 6) & 7, lane = j & 63;
    int quad = lane >> 4, m16 = lane & 15;
    int kb = c * 32;
    const void* W = (kb < K) ? Wl : Wr;
    if (kb >= K) kb -= K;
    int row = ji * 16 + m16;
    size_t src = (size_t)row * K + kb + quad * 8;
    unsigned short out[8];
    #pragma unroll
    for (int t = 0; t < 8; ++t) {
      float v = f32in ? ((const float*)W)[src + t] : b2f(((const unsigned short*)W)[src + t]);
      out[t] = f2b(v);
    }
    *(uint4*)(dst + (size_t)j * 8) = *(const uint4*)out;
  } else if (i < 6272) {
    int o = i - 6144;
    b1_f[o] = f32in ? ((const float*)b1)[o] : b2f(((const unsigned short*)b1)[o]);
  } else if (i < 6400) {
    int o = i - 6272;
    b2_f[o] = f32in ? ((const float*)b2)[o] : b2f(((const unsigned short*)b2)[o]);
  }
}

// ---------- x -> fp8 row-major (gather1 source) + bf16 tiled (gemm1 A2) ----------
// Tiled layout (K8 = K/8 chunks per 16-row tile):
//   elem (n,f) at [((n>>4)*K8 + (f>>3))*128 + (n&15)*8 + (f&7)]
// Gather source is fp8 (64B contiguous rows, half the fill of bf16); the
// ROOT term (xc_til) stays bf16 so only the neighbor-mean is quantized.
__global__ void convert_x_kernel(const void* __restrict__ x_raw,
                                 const int* __restrict__ hdr,
                                 unsigned char* __restrict__ xc8,
                                 unsigned short* __restrict__ xc_til, int n_elems) {
  int i = blockIdx.x * blockDim.x + threadIdx.x;
  if (i >= n_elems) return;
  unsigned short v = hdr[0] ? f2b(((const float*)x_raw)[i]) : ((const unsigned short*)x_raw)[i];
  xc8[i] = f2fp8(b2f(v));
  int n = i >> 6, f = i & 63;
  xc_til[((size_t)(n >> 4) * 8 + (f >> 3)) * 128 + (n & 15) * 8 + (f & 7)] = v;
}

// ---------- P1: per-chunk bucket histogram (LDS atomics, uint4 idx reads) ----------
__global__ __launch_bounds__(256) void hist_chunks_kernel(
    const int* __restrict__ idx_raw, const int* __restrict__ hdr,
    int* __restrict__ H, int n_edges, int NC) {
  __shared__ int h[NBUCKP];
  for (int i = threadIdx.x; i < NBUCKP; i += 256) h[i] = 0;
  __syncthreads();
  const int c = blockIdx.x;
  const int base = c * CHUNK;
  const int lim = min(n_edges - base, CHUNK);
  if (hdr[1]) {  // int64: dst int64 stream at int-offset 2*n_edges + 2e
    const uint4* dp = (const uint4*)(idx_raw + 2 * (size_t)n_edges + 2 * (size_t)base);
    #pragma unroll
    for (int t = 0; t < CHUNK / 512; ++t) {
      int q = t * 256 + threadIdx.x;
      int e = 2 * q;
      if (e < lim) {
        uint4 v = dp[q];
        atomicAdd(&h[((int)v.x) >> 7], 1);
        if (e + 1 < lim) atomicAdd(&h[((int)v.z) >> 7], 1);
      }
    }
  } else {       // int32: dst stream at int-offset n_edges + e
    const uint4* dp = (const uint4*)(idx_raw + (size_t)n_edges + base);
    #pragma unroll
    for (int t = 0; t < CHUNK / 1024; ++t) {
      int q = t * 256 + threadIdx.x;
      int e = 4 * q;
      if (e < lim) {
        uint4 v = dp[q];
        atomicAdd(&h[((int)v.x) >> 7], 1);
        if (e + 1 < lim) atomicAdd(&h[((int)v.y) >> 7], 1);
        if (e + 2 < lim) atomicAdd(&h[((int)v.z) >> 7], 1);
        if (e + 3 < lim) atomicAdd(&h[((int)v.w) >> 7], 1);
      }
    }
  }
  __syncthreads();
  for (int i = threadIdx.x; i < NBUCKP; i += 256) H[(size_t)i * NC + c] = h[i];
}

// ---------- P2: flat exclusive scan of H (NBUCKP*NC ints) ----------
__global__ __launch_bounds__(256) void gscan_sums_kernel(const int* __restrict__ arr,
                                                         int* __restrict__ blockSums, int n) {
  __shared__ int ws[4];
  int tid = threadIdx.x, lane = tid & 63, wid = tid >> 6;
  int base = blockIdx.x * 2048 + tid * 8;
  int s = 0;
  #pragma unroll
  for (int t = 0; t < 8; ++t) {
    int i = base + t;
    if (i < n) s += arr[i];
  }
  #pragma unroll
  for (int m = 1; m < 64; m <<= 1) s += __shfl_xor(s, m, 64);
  if (lane == 0) ws[wid] = s;
  __syncthreads();
  if (tid == 0) blockSums[blockIdx.x] = ws[0] + ws[1] + ws[2] + ws[3];
}

__global__ void gscan_offsets_kernel(const int* __restrict__ blockSums,
                                     int* __restrict__ blockOffs, int nb) {
  int lane = threadIdx.x;  // 64
  int carry = 0;
  for (int start = 0; start < nb; start += 64) {
    int i = start + lane;
    int v = (i < nb) ? blockSums[i] : 0;
    int isc = v;
    #pragma unroll
    for (int off = 1; off < 64; off <<= 1) {
      int t = __shfl_up(isc, off, 64);
      if (lane >= off) isc += t;
    }
    if (i < nb) blockOffs[i] = carry + isc - v;
    carry += __shfl(isc, 63, 64);
  }
}

__global__ __launch_bounds__(256) void gscan_emit_kernel(const int* __restrict__ arr,
                                                         const int* __restrict__ blockOffs,
                                                         int* __restrict__ out, int n) {
  __shared__ int ws[4];
  int tid = threadIdx.x, lane = tid & 63, wid = tid >> 6;
  int base = blockIdx.x * 2048 + tid * 8;
  int v[8];
  int s = 0;
  #pragma unroll
  for (int t = 0; t < 8; ++t) {
    int i = base + t;
    v[t] = (i < n) ? arr[i] : 0;
    s += v[t];
  }
  int isc = s;
  #pragma unroll
  for (int off = 1; off < 64; off <<= 1) {
    int t = __shfl_up(isc, off, 64);
    if (lane >= off) isc += t;
  }
  if (lane == 63) ws[wid] = isc;
  __syncthreads();
  int wb = 0;
  #pragma unroll
  for (int w = 0; w < 4; ++w)
    if (w < wid) wb += ws[w];
  int excl = blockOffs[blockIdx.x] + wb + isc - s;
  #pragma unroll
  for (int t = 0; t < 8; ++t) {
    int i = base + t;
    if (i < n) {
      out[i] = excl;
      excl += v[t];
    }
  }
}

// ---------- P3: scatter (src,dst) into bucket-sorted ebuf (uint4 idx reads) ----------
__global__ __launch_bounds__(256) void scatter_kernel(
    const int* __restrict__ idx_raw, const int* __restrict__ hdr,
    const int* __restrict__ O, unsigned long long* __restrict__ ebuf,
    int n_edges, int NC) {
  __shared__ int base[NBUCKP];
  const int c = blockIdx.x;
  for (int i = threadIdx.x; i < NBUCKP; i += 256) base[i] = O[(size_t)i * NC + c];
  __syncthreads();
  const int eb = c * CHUNK;
  const int lim = min(n_edges - eb, CHUNK);
  if (hdr[1]) {
    const uint4* sp = (const uint4*)(idx_raw + 2 * (size_t)eb);
    const uint4* dp = (const uint4*)(idx_raw + 2 * (size_t)n_edges + 2 * (size_t)eb);
    #pragma unroll
    for (int t = 0; t < CHUNK / 512; ++t) {
      int q = t * 256 + threadIdx.x;
      int e = 2 * q;
      if (e < lim) {
        uint4 sv = sp[q], dv = dp[q];
        int p0 = atomicAdd(&base[((int)dv.x) >> 7], 1);
        ebuf[p0] = (unsigned long long)sv.x | ((unsigned long long)dv.x << 32);
        if (e + 1 < lim) {
          int p1 = atomicAdd(&base[((int)dv.z) >> 7], 1);
          ebuf[p1] = (unsigned long long)sv.z | ((unsigned long long)dv.z << 32);
        }
      }
    }
  } else {
    const uint4* sp = (const uint4*)(idx_raw + (size_t)eb);
    const uint4* dp = (const uint4*)(idx_raw + (size_t)n_edges + eb);
    #pragma unroll
    for (int t = 0; t < CHUNK / 1024; ++t) {
      int q = t * 256 + threadIdx.x;
      int e = 4 * q;
      if (e < lim) {
        uint4 sv = sp[q], dv = dp[q];
        int p0 = atomicAdd(&base[((int)dv.x) >> 7], 1);
        ebuf[p0] = (unsigned long long)sv.x | ((unsigned long long)dv.x << 32);
        if (e + 1 < lim) {
          int p1 = atomicAdd(&base[((int)dv.y) >> 7], 1);
          ebuf[p1] = (unsigned long long)sv.y | ((unsigned long long)dv.y << 32);
        }
        if (e + 2 < lim) {
          int p2 = atomicAdd(&base[((int)dv.z) >> 7], 1);
          ebuf[p2] = (unsigned long long)sv.z | ((unsigned long long)dv.z << 32);
        }
        if (e + 3 < lim) {
          int p3 = atomicAdd(&base[((int)dv.w) >> 7], 1);
          ebuf[p3] = (unsigned long long)sv.w | ((unsigned long long)dv.w << 32);
        }
      }
    }
  }
}

// ---------- P4: per-bucket CSR finalize (contiguous segment, LDS only) ----------
__global__ __launch_bounds__(256) void bucket_csr_kernel(
    const unsigned long long* __restrict__ ebuf, const int* __restrict__ O,
    int* __restrict__ col, int* __restrict__ row_start, float* __restrict__ deg_inv,
    int n_nodes, int n_edges, int NC) {
  __shared__ int cntl[128];
  __shared__ int cur[128];
  __shared__ int w0tot;
  const int b = blockIdx.x, tid = threadIdx.x;
  const int node0 = b << 7;
  const int beg = O[(size_t)b * NC];
  const int end = (b + 1 < NBUCKP) ? O[(size_t)(b + 1) * NC] : n_edges;
  if (tid < 128) cntl[tid] = 0;
  __syncthreads();
  for (int e = beg + tid; e < end; e += 256) {
    int d = (int)(ebuf[e] >> 32);
    atomicAdd(&cntl[d - node0], 1);
  }
  __syncthreads();
  int v = (tid < 128) ? cntl[tid] : 0;
  int lane = tid & 63;
  int isc = v;
  #pragma unroll
  for (int o = 1; o < 64; o <<= 1) {
    int t = __shfl_up(isc, o, 64);
    if (lane >= o) isc += t;
  }
  if (tid == 63) w0tot = isc;
  __syncthreads();
  int incl = isc + ((tid >= 64 && tid < 128) ? w0tot : 0);
  int excl = incl - v;
  if (tid < 128) {
    cur[tid] = excl;
    int node = node0 + tid;
    if (node < n_nodes) {
      row_start[node] = beg + excl;
      deg_inv[node] = 1.0f / (float)((v > 1) ? v : 1);
    }
  }
  __syncthreads();
  for (int e = beg + tid; e < end; e += 256) {
    unsigned long long u = ebuf[e];
    int s = (int)(u & 0xFFFFFFFFull);
    int d = (int)(u >> 32);
    int r = atomicAdd(&cur[d - node0], 1);  // LDS atomic
    col[beg + r] = s;
  }
  if (b == 0 && tid == 0) row_start[n_nodes] = n_edges;
}

// ---------- gather1: 2 nodes/wave; fp8 rows (64B); zero-row sentinel ----------
// Row = 64 fp8 = 64B contiguous. Per node: 32 lanes, rg=(lane&31)>>3 (4 edge
// slots), fq=lane&7 (8 features each, uint2). Tail lanes hold the sentinel
// row index (n_nodes, zeroed). HW pk decode + pk f32 accumulate. Output
// tiled bf16 (layout for gemm1 A1).
__global__ __launch_bounds__(256) void gather1_kernel(
    const unsigned char* __restrict__ x8, const int* __restrict__ row_start,
    const int* __restrict__ col, const float* __restrict__ deg_inv,
    unsigned short* __restrict__ agg1, int n_nodes) {
  int lane = threadIdx.x & 63;
  int n = blockIdx.x * 8 + (threadIdx.x >> 6) * 2 + (lane >> 5);
  if (n >= n_nodes) return;
  int l32 = lane & 31;
  int rg = l32 >> 3, fq = l32 & 7;
  int beg = row_start[n], end = row_start[n + 1];
  f32x2 a[4];
  #pragma unroll
  for (int t = 0; t < 4; ++t) a[t] = (f32x2){0.f, 0.f};
  for (int blk = beg; blk < end; blk += 32) {
    int ce = blk + l32;
    int cc = col[ce < end ? ce : end - 1];
    int cl = (ce < end) ? cc : n_nodes;   // sentinel zero row
    int slv[8];
    #pragma unroll
    for (int k = 0; k < 8; ++k)
      if (blk + 4 * k < end)
        slv[k] = __shfl(cl, 4 * k + rg, 32);  // constant idx, all lanes active
    uint2 p[8];
    #pragma unroll
    for (int k = 0; k < 8; ++k)
      if (blk + 4 * k < end)
        p[k] = *(const uint2*)(x8 + (size_t)slv[k] * 64 + fq * 8);
    #pragma unroll
    for (int k = 0; k < 8; ++k)
      if (blk + 4 * k < end)
        acc8fp8(a, p[k]);  // sentinel rows add 0
  }
  float af[8] = {a[0][0], a[0][1], a[1][0], a[1][1],
                 a[2][0], a[2][1], a[3][0], a[3][1]};
  #pragma unroll
  for (int m = 8; m <= 16; m <<= 1)   // reduce over 4 edge slots (within 32-lane half)
    #pragma unroll
    for (int t = 0; t < 8; ++t) af[t] += __shfl_xor(af[t], m, 64);
  if (rg == 0) {
    float di = deg_inv[n];
    uint4 o;
    o.x = pack2(af[0] * di, af[1] * di);
    o.y = pack2(af[2] * di, af[3] * di);
    o.z = pack2(af[4] * di, af[5] * di);
    o.w = pack2(af[6] * di, af[7] * di);
    // tiled: chunk (n>>4, kc=fq), slot n&15
    *(uint4*)(agg1 + ((size_t)(n >> 4) * 8 + fq) * 128 + (n & 15) * 8) = o;
  }
}

// ---------- gather2: 1 node/wave; fp8 rows (128B); zero-row sentinel; pk decode ----------
// Row = 128 fp8 = 128B contiguous. rg=lane>>4 (4 edge slots), fq=lane&15
// (8 features, uint2). 64-edge col blocks; inner rounds of 32 edges.
__global__ __launch_bounds__(256) void gather2_kernel(
    const unsigned char* __restrict__ h8, const int* __restrict__ row_start,
    const int* __restrict__ col, const float* __restrict__ deg_inv,
    unsigned short* __restrict__ agg2, int n_nodes) {
  int lane = threadIdx.x & 63;
  int n = blockIdx.x * 4 + (threadIdx.x >> 6);
  if (n >= n_nodes) return;
  int rg = lane >> 4, fq = lane & 15;
  int beg = row_start[n], end = row_start[n + 1];
  f32x2 a[4];
  #pragma unroll
  for (int t = 0; t < 4; ++t) a[t] = (f32x2){0.f, 0.f};
  for (int blk = beg; blk < end; blk += 64) {
    int ce = blk + lane;
    int cc = col[ce < end ? ce : end - 1];
    int cl = (ce < end) ? cc : n_nodes;   // sentinel zero row
    int iend = min(end, blk + 64);
    for (int i = blk; i < iend; i += 32) {
      int ib = (i - blk) + rg;  // 0 or 32, + rg
      int slv[8];
      #pragma unroll
      for (int k = 0; k < 8; ++k)
        if (i + 4 * k < end)
          slv[k] = __shfl(cl, ib + 4 * k, 64);  // idx in [0,64), all lanes active
      uint2 p[8];
      #pragma unroll
      for (int k = 0; k < 8; ++k)
        if (i + 4 * k < end)
          p[k] = *(const uint2*)(h8 + (size_t)slv[k] * 128 + (unsigned)fq * 8u);
      #pragma unroll
      for (int k = 0; k < 8; ++k)
        if (i + 4 * k < end)
          acc8fp8(a, p[k]);  // sentinel rows add 0
    }
  }
  float af[8] = {a[0][0], a[0][1], a[1][0], a[1][1],
                 a[2][0], a[2][1], a[3][0], a[3][1]};
  #pragma unroll
  for (int m = 16; m < 64; m <<= 1)
    #pragma unroll
    for (int t = 0; t < 8; ++t) af[t] += __shfl_xor(af[t], m, 64);
  if (rg == 0) {
    float di = deg_inv[n];
    uint4 o;
    o.x = pack2(af[0] * di, af[1] * di);
    o.y = pack2(af[2] * di, af[3] * di);
    o.z = pack2(af[4] * di, af[5] * di);
    o.w = pack2(af[6] * di, af[7] * di);
    // tiled: chunk (n>>4, kc=fq), slot n&15 (K8 = 16)
    *(uint4*)(agg2 + ((size_t)(n >> 4) * 16 + fq) * 128 + (n & 15) * 8) = o;
  }
}

// ---------- MFMA concat-GEMM: C = act([A1|A2] @ [Wl|Wr]^T + b) ----------
// A1 and A2 tiled (fragment-order, 1KB contiguous wave-loads).
// Wf fragment-major: every W load is 64 lanes x 16B contiguous.
// Epilogue: LDS-staged per 16-row half-tile -> wide coalesced stores.
// !FINAL (layer 1): writes C8 (fp8 row-major, gather2 source) + Ctil (bf16
// tiled, gemm2 A2 source). FINAL: row-major f32/bf16 to Cf.
template <int K1, int K2, bool RELU, bool FINAL>
__global__ __launch_bounds__(256, 4) void gemm_mfma(
    const unsigned short* __restrict__ A1, const unsigned short* __restrict__ A2,
    const unsigned short* __restrict__ Wf, const float* __restrict__ bias,
    unsigned char* __restrict__ C8, unsigned short* __restrict__ Ctil,
    void* __restrict__ Cf,
    const int* __restrict__ hdr, int n_nodes) {
  const int tid = threadIdx.x;
  const int wave = tid >> 6, lane = tid & 63;
  const int m16 = lane & 15, quad = lane >> 4;
  const int nb = blockIdx.x * 128 + wave * 32;
  const int t0 = nb >> 4;  // tile index for tiled A (nb is a multiple of 32)

  f32x4 acc[2][8];
  #pragma unroll
  for (int mi = 0; mi < 2; ++mi)
    #pragma unroll
    for (int ji = 0; ji < 8; ++ji) acc[mi][ji] = (f32x4){0.f, 0.f, 0.f, 0.f};

  constexpr int NSTEP = (K1 + K2) / 32;
  constexpr int K8_1 = K1 / 8;
  constexpr int K8_2 = K2 / 8;
  #pragma unroll
  for (int c = 0; c < NSTEP; ++c) {
    const bool first = (c * 32) < K1;
    bf16x8 a0, a1;
    if (first) {
      const unsigned short* p = A1 + (size_t)(t0 * K8_1 + c * 4) * 128 + lane * 8;
      a0 = *(const bf16x8*)p;
      a1 = *(const bf16x8*)(p + K8_1 * 128);
    } else {
      const int cc = c - K1 / 32;
      const unsigned short* p = A2 + (size_t)(t0 * K8_2 + cc * 4) * 128 + lane * 8;
      a0 = *(const bf16x8*)p;
      a1 = *(const bf16x8*)(p + K8_2 * 128);
    }
    bf16x8 w[8];
    #pragma unroll
    for (int ji = 0; ji < 8; ++ji)
      w[ji] = *(const bf16x8*)(Wf + ((size_t)(c * 8 + ji) * 64 + lane) * 8);
    #pragma unroll
    for (int ji = 0; ji < 8; ++ji) {
      acc[0][ji] = __builtin_amdgcn_mfma_f32_16x16x32_bf16(a0, w[ji], acc[0][ji], 0, 0, 0);
      acc[1][ji] = __builtin_amdgcn_mfma_f32_16x16x32_bf16(a1, w[ji], acc[1][ji], 0, 0, 0);
    }
  }

  // ---- LDS-staged epilogue: per-wave [16][132] f32 tile (pad +4 words) ----
  __shared__ float stage[4][16][132];
  float (*S)[132] = stage[wave];
  const bool f32out = FINAL && (hdr[0] == 1);

  #pragma unroll
  for (int mi = 0; mi < 2; ++mi) {
    __syncthreads();  // protect against WAR with previous half-tile readback
    #pragma unroll
    for (int ji = 0; ji < 8; ++ji) {
      int j = ji * 16 + m16;
      float bj = bias[j];
      #pragma unroll
      for (int r = 0; r < 4; ++r) {
        float v = acc[mi][ji][r] + bj;
        if (RELU) v = fmaxf(v, 0.f);
        S[quad * 4 + r][j] = v;
      }
    }
    __syncthreads();
    const int nbase = nb + mi * 16;
    if (FINAL) {
      #pragma unroll
      for (int rd = 0; rd < 8; ++rd) {
        int q = rd * 64 + lane;
        int row = q >> 5, col4 = q & 31;
        float4 v = *(const float4*)&S[row][col4 * 4];
        int n = nbase + row;
        if (n < n_nodes) {
          if (f32out) {
            *(float4*)((float*)Cf + (size_t)n * 128 + col4 * 4) = v;
          } else {
            uint2 o;
            o.x = pack2(v.x, v.y);
            o.y = pack2(v.z, v.w);
            *(uint2*)((unsigned short*)Cf + (size_t)n * 128 + col4 * 4) = o;
          }
        }
      }
    } else {
      // C8: 4 rounds; 16 lanes cover one 128B fp8 row contiguously
      #pragma unroll
      for (int rd = 0; rd < 4; ++rd) {
        int row = rd * 4 + (lane >> 4), c8 = lane & 15;
        float4 v0 = *(const float4*)&S[row][c8 * 8];
        float4 v1 = *(const float4*)&S[row][c8 * 8 + 4];
        int n = nbase + row;
        if (n < n_nodes) {
          unsigned int lo = (unsigned)f2fp8(v0.x) | ((unsigned)f2fp8(v0.y) << 8) |
                            ((unsigned)f2fp8(v0.z) << 16) | ((unsigned)f2fp8(v0.w) << 24);
          unsigned int hi = (unsigned)f2fp8(v1.x) | ((unsigned)f2fp8(v1.y) << 8) |
                            ((unsigned)f2fp8(v1.z) << 16) | ((unsigned)f2fp8(v1.w) << 24);
          *(uint2*)(C8 + (size_t)n * 128 + c8 * 8) = (uint2){lo, hi};
        }
      }
      // Ctil: 4 rounds; 16 lanes cover one 256B tiled chunk contiguously
      const int tile = nbase >> 4;
      #pragma unroll
      for (int rd = 0; rd < 4; ++rd) {
        int n16 = lane & 15, c2 = rd * 4 + (lane >> 4);
        float4 v0 = *(const float4*)&S[n16][c2 * 8];
        float4 v1 = *(const float4*)&S[n16][c2 * 8 + 4];
        int n = nbase + n16;
        if (n < n_nodes) {
          uint4 o;
          o.x = pack2(v0.x, v0.y); o.y = pack2(v0.z, v0.w);
          o.z = pack2(v1.x, v1.y); o.w = pack2(v1.z, v1.w);
          *(uint4*)(Ctil + ((size_t)(tile * 16 + c2)) * 128 + n16 * 8) = o;
        }
      }
    }
  }
}

// ---------- launch ----------
extern "C" void kernel_launch(void* const* d_in, const int* in_sizes, int n_in,
                              void* d_out, int out_size, void* d_ws, size_t ws_size,
                              hipStream_t stream) {
  const void* x_raw  = d_in[0];
  const int* idx_raw = (const int*)d_in[1];
  const void* W1l = d_in[2];
  const void* b1  = d_in[3];
  const void* W1r = d_in[4];
  const void* W2l = d_in[5];
  const void* b2  = d_in[6];
  const void* W2r = d_in[7];
  const int N = in_sizes[0] / 64;
  const int E = in_sizes[1] / 2;
  const int NP = (N + 127) & ~127;  // padded rows for tiled buffers
  const int NC = (E + CHUNK - 1) / CHUNK;
  const int NSCAN = NBUCKP * NC;
  const int NBs = (NSCAN + 2047) / 2048;
  const int NBUCK = (N + 127) >> 7;

  char* ws = (char*)d_ws;
  size_t off = 0;
  auto alloc = [&](size_t bytes) {
    char* p = ws + off;
    off = (off + bytes + 511) & ~((size_t)511);
    return p;
  };
  int* hdr        = (int*)alloc(512);
  int* H          = (int*)alloc((size_t)NSCAN * 4);
  int* O          = (int*)alloc((size_t)NSCAN * 4);
  int* blockSums  = (int*)alloc((size_t)NBs * 4);
  int* blockOffs  = (int*)alloc((size_t)NBs * 4);
  unsigned long long* ebuf = (unsigned long long*)alloc((size_t)E * 8);
  int* col        = (int*)alloc((size_t)E * 4);
  int* row_start  = (int*)alloc(((size_t)N + 1) * 4);
  float* deg_inv  = (float*)alloc((size_t)N * 4);
  unsigned short* Wf1 = (unsigned short*)alloc(32768);
  unsigned short* Wf2 = (unsigned short*)alloc(65536);
  float* b1_f     = (float*)alloc(512);
  float* b2_f     = (float*)alloc(512);
  unsigned char*  xc8     = (unsigned char*)alloc(((size_t)N + 1) * 64);        // +1 sentinel row
  unsigned short* xc_til  = (unsigned short*)alloc((size_t)NP * 64 * 2);
  unsigned short* agg1    = (unsigned short*)alloc((size_t)NP * 64 * 2);
  unsigned char*  hbuf8   = (unsigned char*)alloc(((size_t)N + 1) * 128);       // +1 sentinel row
  unsigned short* hbuf_til= (unsigned short*)alloc((size_t)NP * 128 * 2);
  unsigned short* agg2    = (unsigned short*)alloc((size_t)NP * 128 * 2);

  detect_kernel<<<1, 64, 0, stream>>>(x_raw, idx_raw, hdr,
                                      xc8 + (size_t)N * 64, hbuf8 + (size_t)N * 128);
  reorder_w_kernel<<<(6400 + 255) / 256, 256, 0, stream>>>(
      W1l, W1r, W2l, W2r, b1, b2, hdr, Wf1, Wf2, b1_f, b2_f);
  convert_x_kernel<<<(N * 64 + 255) / 256, 256, 0, stream>>>(x_raw, hdr, xc8, xc_til, N * 64);
  hist_chunks_kernel<<<NC, 256, 0, stream>>>(idx_raw, hdr, H, E, NC);
  gscan_sums_kernel<<<NBs, 256, 0, stream>>>(H, blockSums, NSCAN);
  gscan_offsets_kernel<<<1, 64, 0, stream>>>(blockSums, blockOffs, NBs);
  gscan_emit_kernel<<<NBs, 256, 0, stream>>>(H, blockOffs, O, NSCAN);
  scatter_kernel<<<NC, 256, 0, stream>>>(idx_raw, hdr, O, ebuf, E, NC);
  bucket_csr_kernel<<<NBUCK, 256, 0, stream>>>(ebuf, O, col, row_start, deg_inv, N, E, NC);
  gather1_kernel<<<(N + 7) / 8, 256, 0, stream>>>(xc8, row_start, col, deg_inv, agg1, N);
  gemm_mfma<64, 64, true, false><<<(N + 127) / 128, 256, 0, stream>>>(
      agg1, xc_til, Wf1, b1_f, hbuf8, hbuf_til, nullptr, hdr, N);
  gather2_kernel<<<(N + 3) / 4, 256, 0, stream>>>(hbuf8, row_start, col, deg_inv, agg2, N);
  gemm_mfma<128, 128, false, true><<<(N + 127) / 128, 256, 0, stream>>>(
      agg2, hbuf_til, Wf2, b2_f, nullptr, nullptr, d_out, hdr, N);
}

// Round 11
// 255.450 us; speedup vs baseline: 1.1983x; 1.0086x over previous
//
#include <hip/hip_runtime.h>
#include <hip/hip_bf16.h>
#include <hip/hip_fp8.h>

// ---------- helpers ----------
__device__ __forceinline__ float b2f(unsigned short u) {
  return __uint_as_float(((unsigned int)u) << 16);
}
__device__ __forceinline__ unsigned short f2b(float f) {
  unsigned int x = __float_as_uint(f);
  unsigned int r = x + 0x7FFFu + ((x >> 16) & 1u);  // RNE
  return (unsigned short)(r >> 16);
}
__device__ __forceinline__ unsigned int pack2(float lo, float hi) {
  return (unsigned int)f2b(lo) | ((unsigned int)f2b(hi) << 16);
}
// fp8 e4m3 (OCP) scalar encode via HIP type (HW cvt on gfx950)
__device__ __forceinline__ unsigned char f2fp8(float f) {
  __hip_fp8_e4m3 q(f);
  return (unsigned char)q.__x;
}

typedef short bf16x8 __attribute__((ext_vector_type(8)));  // 8 bf16 = 4 VGPRs
typedef float f32x4 __attribute__((ext_vector_type(4)));
typedef float f32x2 __attribute__((ext_vector_type(2)));

// HW packed fp8 decode + packed f32 accumulate: 8 features = 4 cvt_pk + 4 pk_add.
// Byte k of the row = feature k; cvt_pk(word,false) -> bytes 0,1 = (.x,.y).
__device__ __forceinline__ void acc8fp8(f32x2* a, uint2 p) {
  a[0] += __builtin_amdgcn_cvt_pk_f32_fp8(p.x, false);
  a[1] += __builtin_amdgcn_cvt_pk_f32_fp8(p.x, true);
  a[2] += __builtin_amdgcn_cvt_pk_f32_fp8(p.y, false);
  a[3] += __builtin_amdgcn_cvt_pk_f32_fp8(p.y, true);
}

#define CHUNK 8192          // edges per P1/P3 block
#define NBUCKP 1024         // padded bucket count (bucket = dst >> 7, N <= 131072)

// ---------- dtype detection + zero-row init ----------
// hdr[0]: 0 = floats are bf16, 1 = floats are f32
// hdr[1]: 0 = edge_index int32, 1 = int64
// Zeroes sentinel rows (index N) of xc8 (64B) and hbuf8 (128B): ragged gather
// tails read these rows UNCONDITIONALLY and accumulate 0 (no slot guards).
__global__ void detect_kernel(const void* __restrict__ x_raw,
                              const void* __restrict__ idx_raw,
                              int* __restrict__ hdr,
                              unsigned char* __restrict__ x8_z,
                              unsigned char* __restrict__ h8_z) {
  int lane = threadIdx.x;  // 64 threads
  if (lane < 4) ((uint4*)x8_z)[lane] = (uint4){0u, 0u, 0u, 0u};
  else if (lane < 12) ((uint4*)h8_z)[lane - 4] = (uint4){0u, 0u, 0u, 0u};
  const unsigned short* xb = (const unsigned short*)x_raw;
  unsigned short u = xb[2 * lane];
  int e = (u >> 7) & 0xFF;
  bool sane = ((u & 0x7FFFu) == 0) || (e >= 107 && e <= 137);
  unsigned long long m = __ballot(sane);
  const int* ib = (const int*)idx_raw;
  int v = ib[2 * lane + 1];
  unsigned long long m2 = __ballot(v != 0);
  if (lane == 0) {
    hdr[0] = (__popcll(m) >= 32) ? 0 : 1;
    hdr[1] = (m2 == 0ull) ? 1 : 0;
  }
}

// ---------- weights -> fragment-major bf16 (Wf), biases -> f32 ----------
// Wf layout: chunk index (c*8 + ji), 64 lanes of 8 bf16 each (16B).
__global__ void reorder_w_kernel(const void* __restrict__ W1l, const void* __restrict__ W1r,
                                 const void* __restrict__ W2l, const void* __restrict__ W2r,
                                 const void* __restrict__ b1, const void* __restrict__ b2,
                                 const int* __restrict__ hdr,
                                 unsigned short* __restrict__ Wf1, unsigned short* __restrict__ Wf2,
                                 float* __restrict__ b1_f, float* __restrict__ b2_f) {
  int i = blockIdx.x * blockDim.x + threadIdx.x;
  const bool f32in = hdr[0] != 0;
  if (i < 6144) {
    const void* Wl; const void* Wr; int K; unsigned short* dst; int j;
    if (i < 2048) { Wl = W1l; Wr = W1r; K = 64;  dst = Wf1; j = i; }
    else          { Wl = W2l; Wr = W2r; K = 128; dst = Wf2; j = i - 2048; }
    int c = j >> 9, ji = (j >> 6) & 7, lane = j & 63;
    int quad = lane >> 4, m16 = lane & 15;
    int kb = c * 32;
    const void* W = (kb < K) ? Wl : Wr;
    if (kb >= K) kb -= K;
    int row = ji * 16 + m16;
    size_t src = (size_t)row * K + kb + quad * 8;
    unsigned short out[8];
    #pragma unroll
    for (int t = 0; t < 8; ++t) {
      float v = f32in ? ((const float*)W)[src + t] : b2f(((const unsigned short*)W)[src + t]);
      out[t] = f2b(v);
    }
    *(uint4*)(dst + (size_t)j * 8) = *(const uint4*)out;
  } else if (i < 6272) {
    int o = i - 6144;
    b1_f[o] = f32in ? ((const float*)b1)[o] : b2f(((const unsigned short*)b1)[o]);
  } else if (i < 6400) {
    int o = i - 6272;
    b2_f[o] = f32in ? ((const float*)b2)[o] : b2f(((const unsigned short*)b2)[o]);
  }
}

// ---------- x -> fp8 row-major (gather1 source) + bf16 tiled (gemm1 A2) ----------
// Tiled layout (K8 = K/8 chunks per 16-row tile):
//   elem (n,f) at [((n>>4)*K8 + (f>>3))*128 + (n&15)*8 + (f&7)]
// Gather source is fp8 (64B contiguous rows, half the fill of bf16); the
// ROOT term (xc_til) stays bf16 so only the neighbor-mean is quantized.
__global__ void convert_x_kernel(const void* __restrict__ x_raw,
                                 const int* __restrict__ hdr,
                                 unsigned char* __restrict__ xc8,
                                 unsigned short* __restrict__ xc_til, int n_elems) {
  int i = blockIdx.x * blockDim.x + threadIdx.x;
  if (i >= n_elems) return;
  unsigned short v = hdr[0] ? f2b(((const float*)x_raw)[i]) : ((const unsigned short*)x_raw)[i];
  xc8[i] = f2fp8(b2f(v));
  int n = i >> 6, f = i & 63;
  xc_til[((size_t)(n >> 4) * 8 + (f >> 3)) * 128 + (n & 15) * 8 + (f & 7)] = v;
}

// ---------- P1: per-chunk bucket histogram (LDS atomics, uint4 idx reads) ----------
__global__ __launch_bounds__(256) void hist_chunks_kernel(
    const int* __restrict__ idx_raw, const int* __restrict__ hdr,
    int* __restrict__ H, int n_edges, int NC) {
  __shared__ int h[NBUCKP];
  for (int i = threadIdx.x; i < NBUCKP; i += 256) h[i] = 0;
  __syncthreads();
  const int c = blockIdx.x;
  const int base = c * CHUNK;
  const int lim = min(n_edges - base, CHUNK);
  if (hdr[1]) {  // int64: dst int64 stream at int-offset 2*n_edges + 2e
    const uint4* dp = (const uint4*)(idx_raw + 2 * (size_t)n_edges + 2 * (size_t)base);
    #pragma unroll
    for (int t = 0; t < CHUNK / 512; ++t) {
      int q = t * 256 + threadIdx.x;
      int e = 2 * q;
      if (e < lim) {
        uint4 v = dp[q];
        atomicAdd(&h[((int)v.x) >> 7], 1);
        if (e + 1 < lim) atomicAdd(&h[((int)v.z) >> 7], 1);
      }
    }
  } else {       // int32: dst stream at int-offset n_edges + e
    const uint4* dp = (const uint4*)(idx_raw + (size_t)n_edges + base);
    #pragma unroll
    for (int t = 0; t < CHUNK / 1024; ++t) {
      int q = t * 256 + threadIdx.x;
      int e = 4 * q;
      if (e < lim) {
        uint4 v = dp[q];
        atomicAdd(&h[((int)v.x) >> 7], 1);
        if (e + 1 < lim) atomicAdd(&h[((int)v.y) >> 7], 1);
        if (e + 2 < lim) atomicAdd(&h[((int)v.z) >> 7], 1);
        if (e + 3 < lim) atomicAdd(&h[((int)v.w) >> 7], 1);
      }
    }
  }
  __syncthreads();
  for (int i = threadIdx.x; i < NBUCKP; i += 256) H[(size_t)i * NC + c] = h[i];
}

// ---------- P2: flat exclusive scan of H (NBUCKP*NC ints) ----------
__global__ __launch_bounds__(256) void gscan_sums_kernel(const int* __restrict__ arr,
                                                         int* __restrict__ blockSums, int n) {
  __shared__ int ws[4];
  int tid = threadIdx.x, lane = tid & 63, wid = tid >> 6;
  int base = blockIdx.x * 2048 + tid * 8;
  int s = 0;
  #pragma unroll
  for (int t = 0; t < 8; ++t) {
    int i = base + t;
    if (i < n) s += arr[i];
  }
  #pragma unroll
  for (int m = 1; m < 64; m <<= 1) s += __shfl_xor(s, m, 64);
  if (lane == 0) ws[wid] = s;
  __syncthreads();
  if (tid == 0) blockSums[blockIdx.x] = ws[0] + ws[1] + ws[2] + ws[3];
}

__global__ void gscan_offsets_kernel(const int* __restrict__ blockSums,
                                     int* __restrict__ blockOffs, int nb) {
  int lane = threadIdx.x;  // 64
  int carry = 0;
  for (int start = 0; start < nb; start += 64) {
    int i = start + lane;
    int v = (i < nb) ? blockSums[i] : 0;
    int isc = v;
    #pragma unroll
    for (int off = 1; off < 64; off <<= 1) {
      int t = __shfl_up(isc, off, 64);
      if (lane >= off) isc += t;
    }
    if (i < nb) blockOffs[i] = carry + isc - v;
    carry += __shfl(isc, 63, 64);
  }
}

__global__ __launch_bounds__(256) void gscan_emit_kernel(const int* __restrict__ arr,
                                                         const int* __restrict__ blockOffs,
                                                         int* __restrict__ out, int n) {
  __shared__ int ws[4];
  int tid = threadIdx.x, lane = tid & 63, wid = tid >> 6;
  int base = blockIdx.x * 2048 + tid * 8;
  int v[8];
  int s = 0;
  #pragma unroll
  for (int t = 0; t < 8; ++t) {
    int i = base + t;
    v[t] = (i < n) ? arr[i] : 0;
    s += v[t];
  }
  int isc = s;
  #pragma unroll
  for (int off = 1; off < 64; off <<= 1) {
    int t = __shfl_up(isc, off, 64);
    if (lane >= off) isc += t;
  }
  if (lane == 63) ws[wid] = isc;
  __syncthreads();
  int wb = 0;
  #pragma unroll
  for (int w = 0; w < 4; ++w)
    if (w < wid) wb += ws[w];
  int excl = blockOffs[blockIdx.x] + wb + isc - s;
  #pragma unroll
  for (int t = 0; t < 8; ++t) {
    int i = base + t;
    if (i < n) {
      out[i] = excl;
      excl += v[t];
    }
  }
}

// ---------- P3: scatter (src,dst) into bucket-sorted ebuf (uint4 idx reads) ----------
__global__ __launch_bounds__(256) void scatter_kernel(
    const int* __restrict__ idx_raw, const int* __restrict__ hdr,
    const int* __restrict__ O, unsigned long long* __restrict__ ebuf,
    int n_edges, int NC) {
  __shared__ int base[NBUCKP];
  const int c = blockIdx.x;
  for (int i = threadIdx.x; i < NBUCKP; i += 256) base[i] = O[(size_t)i * NC + c];
  __syncthreads();
  const int eb = c * CHUNK;
  const int lim = min(n_edges - eb, CHUNK);
  if (hdr[1]) {
    const uint4* sp = (const uint4*)(idx_raw + 2 * (size_t)eb);
    const uint4* dp = (const uint4*)(idx_raw + 2 * (size_t)n_edges + 2 * (size_t)eb);
    #pragma unroll
    for (int t = 0; t < CHUNK / 512; ++t) {
      int q = t * 256 + threadIdx.x;
      int e = 2 * q;
      if (e < lim) {
        uint4 sv = sp[q], dv = dp[q];
        int p0 = atomicAdd(&base[((int)dv.x) >> 7], 1);
        ebuf[p0] = (unsigned long long)sv.x | ((unsigned long long)dv.x << 32);
        if (e + 1 < lim) {
          int p1 = atomicAdd(&base[((int)dv.z) >> 7], 1);
          ebuf[p1] = (unsigned long long)sv.z | ((unsigned long long)dv.z << 32);
        }
      }
    }
  } else {
    const uint4* sp = (const uint4*)(idx_raw + (size_t)eb);
    const uint4* dp = (const uint4*)(idx_raw + (size_t)n_edges + eb);
    #pragma unroll
    for (int t = 0; t < CHUNK / 1024; ++t) {
      int q = t * 256 + threadIdx.x;
      int e = 4 * q;
      if (e < lim) {
        uint4 sv = sp[q], dv = dp[q];
        int p0 = atomicAdd(&base[((int)dv.x) >> 7], 1);
        ebuf[p0] = (unsigned long long)sv.x | ((unsigned long long)dv.x << 32);
        if (e + 1 < lim) {
          int p1 = atomicAdd(&base[((int)dv.y) >> 7], 1);
          ebuf[p1] = (unsigned long long)sv.y | ((unsigned long long)dv.y << 32);
        }
        if (e + 2 < lim) {
          int p2 = atomicAdd(&base[((int)dv.z) >> 7], 1);
          ebuf[p2] = (unsigned long long)sv.z | ((unsigned long long)dv.z << 32);
        }
        if (e + 3 < lim) {
          int p3 = atomicAdd(&base[((int)dv.w) >> 7], 1);
          ebuf[p3] = (unsigned long long)sv.w | ((unsigned long long)dv.w << 32);
        }
      }
    }
  }
}

// ---------- P4: per-bucket CSR finalize (contiguous segment, LDS only) ----------
__global__ __launch_bounds__(256) void bucket_csr_kernel(
    const unsigned long long* __restrict__ ebuf, const int* __restrict__ O,
    int* __restrict__ col, int* __restrict__ row_start, float* __restrict__ deg_inv,
    int n_nodes, int n_edges, int NC) {
  __shared__ int cntl[128];
  __shared__ int cur[128];
  __shared__ int w0tot;
  const int b = blockIdx.x, tid = threadIdx.x;
  const int node0 = b << 7;
  const int beg = O[(size_t)b * NC];
  const int end = (b + 1 < NBUCKP) ? O[(size_t)(b + 1) * NC] : n_edges;
  if (tid < 128) cntl[tid] = 0;
  __syncthreads();
  for (int e = beg + tid; e < end; e += 256) {
    int d = (int)(ebuf[e] >> 32);
    atomicAdd(&cntl[d - node0], 1);
  }
  __syncthreads();
  int v = (tid < 128) ? cntl[tid] : 0;
  int lane = tid & 63;
  int isc = v;
  #pragma unroll
  for (int o = 1; o < 64; o <<= 1) {
    int t = __shfl_up(isc, o, 64);
    if (lane >= o) isc += t;
  }
  if (tid == 63) w0tot = isc;
  __syncthreads();
  int incl = isc + ((tid >= 64 && tid < 128) ? w0tot : 0);
  int excl = incl - v;
  if (tid < 128) {
    cur[tid] = excl;
    int node = node0 + tid;
    if (node < n_nodes) {
      row_start[node] = beg + excl;
      deg_inv[node] = 1.0f / (float)((v > 1) ? v : 1);
    }
  }
  __syncthreads();
  for (int e = beg + tid; e < end; e += 256) {
    unsigned long long u = ebuf[e];
    int s = (int)(u & 0xFFFFFFFFull);
    int d = (int)(u >> 32);
    int r = atomicAdd(&cur[d - node0], 1);  // LDS atomic
    col[beg + r] = s;
  }
  if (b == 0 && tid == 0) row_start[n_nodes] = n_edges;
}

// ---------- gather1: 2 nodes/wave; fp8 rows (64B); UNGUARDED slots ----------
// Row = 64 fp8 = 64B contiguous. Per node: 32 lanes, rg=(lane&31)>>3 (4 edge
// slots), fq=lane&7 (8 features each, uint2). All 8 slots run unconditionally:
// tail slots shfl the sentinel index (n_nodes, zeroed row) and accumulate 0.
// Straight-line body -> 8 loads issue back-to-back. 32-bit saddr addressing.
__global__ __launch_bounds__(256) void gather1_kernel(
    const unsigned char* __restrict__ x8, const int* __restrict__ row_start,
    const int* __restrict__ col, const float* __restrict__ deg_inv,
    unsigned short* __restrict__ agg1, int n_nodes) {
  int lane = threadIdx.x & 63;
  int n = blockIdx.x * 8 + (threadIdx.x >> 6) * 2 + (lane >> 5);
  if (n >= n_nodes) return;
  int l32 = lane & 31;
  int rg = l32 >> 3, fq = l32 & 7;
  const unsigned fq8 = (unsigned)fq * 8u;
  int beg = row_start[n], end = row_start[n + 1];
  f32x2 a[4];
  #pragma unroll
  for (int t = 0; t < 4; ++t) a[t] = (f32x2){0.f, 0.f};
  for (int blk = beg; blk < end; blk += 32) {
    int ce = blk + l32;
    int cc = col[ce < end ? ce : end - 1];
    int cl = (ce < end) ? cc : n_nodes;   // sentinel zero row
    int slv[8];
    #pragma unroll
    for (int k = 0; k < 8; ++k)
      slv[k] = __shfl(cl, 4 * k + rg, 32);
    uint2 p[8];
    #pragma unroll
    for (int k = 0; k < 8; ++k)
      p[k] = *(const uint2*)(x8 + (((unsigned)slv[k] << 6) | fq8));
    #pragma unroll
    for (int k = 0; k < 8; ++k)
      acc8fp8(a, p[k]);  // sentinel rows add 0
  }
  float af[8] = {a[0][0], a[0][1], a[1][0], a[1][1],
                 a[2][0], a[2][1], a[3][0], a[3][1]};
  #pragma unroll
  for (int m = 8; m <= 16; m <<= 1)   // reduce over 4 edge slots (within 32-lane half)
    #pragma unroll
    for (int t = 0; t < 8; ++t) af[t] += __shfl_xor(af[t], m, 64);
  if (rg == 0) {
    float di = deg_inv[n];
    uint4 o;
    o.x = pack2(af[0] * di, af[1] * di);
    o.y = pack2(af[2] * di, af[3] * di);
    o.z = pack2(af[4] * di, af[5] * di);
    o.w = pack2(af[6] * di, af[7] * di);
    // tiled: chunk (n>>4, kc=fq), slot n&15
    *(uint4*)(agg1 + ((size_t)(n >> 4) * 8 + fq) * 128 + (n & 15) * 8) = o;
  }
}

// ---------- gather2: 1 node/wave; fp8 rows (128B); UNGUARDED slots ----------
// Row = 128 fp8 = 128B contiguous. rg=lane>>4 (4 edge slots), fq=lane&15
// (8 features, uint2). 64-edge col blocks; inner rounds of 32 edges, all 8
// slots unconditional (sentinel zero row covers tails). 32-bit saddr addr.
__global__ __launch_bounds__(256) void gather2_kernel(
    const unsigned char* __restrict__ h8, const int* __restrict__ row_start,
    const int* __restrict__ col, const float* __restrict__ deg_inv,
    unsigned short* __restrict__ agg2, int n_nodes) {
  int lane = threadIdx.x & 63;
  int n = blockIdx.x * 4 + (threadIdx.x >> 6);
  if (n >= n_nodes) return;
  int rg = lane >> 4, fq = lane & 15;
  const unsigned fq8 = (unsigned)fq * 8u;
  int beg = row_start[n], end = row_start[n + 1];
  f32x2 a[4];
  #pragma unroll
  for (int t = 0; t < 4; ++t) a[t] = (f32x2){0.f, 0.f};
  for (int blk = beg; blk < end; blk += 64) {
    int ce = blk + lane;
    int cc = col[ce < end ? ce : end - 1];
    int cl = (ce < end) ? cc : n_nodes;   // sentinel zero row
    int iend = min(end, blk + 64);
    for (int i = blk; i < iend; i += 32) {
      int ib = (i - blk) + rg;  // 0 or 32, + rg
      int slv[8];
      #pragma unroll
      for (int k = 0; k < 8; ++k)
        slv[k] = __shfl(cl, ib + 4 * k, 64);
      uint2 p[8];
      #pragma unroll
      for (int k = 0; k < 8; ++k)
        p[k] = *(const uint2*)(h8 + (((unsigned)slv[k] << 7) | fq8));
      #pragma unroll
      for (int k = 0; k < 8; ++k)
        acc8fp8(a, p[k]);  // sentinel rows add 0
    }
  }
  float af[8] = {a[0][0], a[0][1], a[1][0], a[1][1],
                 a[2][0], a[2][1], a[3][0], a[3][1]};
  #pragma unroll
  for (int m = 16; m < 64; m <<= 1)
    #pragma unroll
    for (int t = 0; t < 8; ++t) af[t] += __shfl_xor(af[t], m, 64);
  if (rg == 0) {
    float di = deg_inv[n];
    uint4 o;
    o.x = pack2(af[0] * di, af[1] * di);
    o.y = pack2(af[2] * di, af[3] * di);
    o.z = pack2(af[4] * di, af[5] * di);
    o.w = pack2(af[6] * di, af[7] * di);
    // tiled: chunk (n>>4, kc=fq), slot n&15 (K8 = 16)
    *(uint4*)(agg2 + ((size_t)(n >> 4) * 16 + fq) * 128 + (n & 15) * 8) = o;
  }
}

// ---------- MFMA concat-GEMM: C = act([A1|A2] @ [Wl|Wr]^T + b) ----------
// A1 and A2 tiled (fragment-order, 1KB contiguous wave-loads).
// Wf fragment-major: every W load is 64 lanes x 16B contiguous.
// Epilogue: LDS-staged per 16-row half-tile -> wide coalesced stores.
// !FINAL (layer 1): writes C8 (fp8 row-major, gather2 source) + Ctil (bf16
// tiled, gemm2 A2 source). FINAL: row-major f32/bf16 to Cf.
template <int K1, int K2, bool RELU, bool FINAL>
__global__ __launch_bounds__(256, 4) void gemm_mfma(
    const unsigned short* __restrict__ A1, const unsigned short* __restrict__ A2,
    const unsigned short* __restrict__ Wf, const float* __restrict__ bias,
    unsigned char* __restrict__ C8, unsigned short* __restrict__ Ctil,
    void* __restrict__ Cf,
    const int* __restrict__ hdr, int n_nodes) {
  const int tid = threadIdx.x;
  const int wave = tid >> 6, lane = tid & 63;
  const int m16 = lane & 15, quad = lane >> 4;
  const int nb = blockIdx.x * 128 + wave * 32;
  const int t0 = nb >> 4;  // tile index for tiled A (nb is a multiple of 32)

  f32x4 acc[2][8];
  #pragma unroll
  for (int mi = 0; mi < 2; ++mi)
    #pragma unroll
    for (int ji = 0; ji < 8; ++ji) acc[mi][ji] = (f32x4){0.f, 0.f, 0.f, 0.f};

  constexpr int NSTEP = (K1 + K2) / 32;
  constexpr int K8_1 = K1 / 8;
  constexpr int K8_2 = K2 / 8;
  #pragma unroll
  for (int c = 0; c < NSTEP; ++c) {
    const bool first = (c * 32) < K1;
    bf16x8 a0, a1;
    if (first) {
      const unsigned short* p = A1 + (size_t)(t0 * K8_1 + c * 4) * 128 + lane * 8;
      a0 = *(const bf16x8*)p;
      a1 = *(const bf16x8*)(p + K8_1 * 128);
    } else {
      const int cc = c - K1 / 32;
      const unsigned short* p = A2 + (size_t)(t0 * K8_2 + cc * 4) * 128 + lane * 8;
      a0 = *(const bf16x8*)p;
      a1 = *(const bf16x8*)(p + K8_2 * 128);
    }
    bf16x8 w[8];
    #pragma unroll
    for (int ji = 0; ji < 8; ++ji)
      w[ji] = *(const bf16x8*)(Wf + ((size_t)(c * 8 + ji) * 64 + lane) * 8);
    #pragma unroll
    for (int ji = 0; ji < 8; ++ji) {
      acc[0][ji] = __builtin_amdgcn_mfma_f32_16x16x32_bf16(a0, w[ji], acc[0][ji], 0, 0, 0);
      acc[1][ji] = __builtin_amdgcn_mfma_f32_16x16x32_bf16(a1, w[ji], acc[1][ji], 0, 0, 0);
    }
  }

  // ---- LDS-staged epilogue: per-wave [16][132] f32 tile (pad +4 words) ----
  __shared__ float stage[4][16][132];
  float (*S)[132] = stage[wave];
  const bool f32out = FINAL && (hdr[0] == 1);

  #pragma unroll
  for (int mi = 0; mi < 2; ++mi) {
    __syncthreads();  // protect against WAR with previous half-tile readback
    #pragma unroll
    for (int ji = 0; ji < 8; ++ji) {
      int j = ji * 16 + m16;
      float bj = bias[j];
      #pragma unroll
      for (int r = 0; r < 4; ++r) {
        float v = acc[mi][ji][r] + bj;
        if (RELU) v = fmaxf(v, 0.f);
        S[quad * 4 + r][j] = v;
      }
    }
    __syncthreads();
    const int nbase = nb + mi * 16;
    if (FINAL) {
      #pragma unroll
      for (int rd = 0; rd < 8; ++rd) {
        int q = rd * 64 + lane;
        int row = q >> 5, col4 = q & 31;
        float4 v = *(const float4*)&S[row][col4 * 4];
        int n = nbase + row;
        if (n < n_nodes) {
          if (f32out) {
            *(float4*)((float*)Cf + (size_t)n * 128 + col4 * 4) = v;
          } else {
            uint2 o;
            o.x = pack2(v.x, v.y);
            o.y = pack2(v.z, v.w);
            *(uint2*)((unsigned short*)Cf + (size_t)n * 128 + col4 * 4) = o;
          }
        }
      }
    } else {
      // C8: 4 rounds; 16 lanes cover one 128B fp8 row contiguously
      #pragma unroll
      for (int rd = 0; rd < 4; ++rd) {
        int row = rd * 4 + (lane >> 4), c8 = lane & 15;
        float4 v0 = *(const float4*)&S[row][c8 * 8];
        float4 v1 = *(const float4*)&S[row][c8 * 8 + 4];
        int n = nbase + row;
        if (n < n_nodes) {
          unsigned int lo = (unsigned)f2fp8(v0.x) | ((unsigned)f2fp8(v0.y) << 8) |
                            ((unsigned)f2fp8(v0.z) << 16) | ((unsigned)f2fp8(v0.w) << 24);
          unsigned int hi = (unsigned)f2fp8(v1.x) | ((unsigned)f2fp8(v1.y) << 8) |
                            ((unsigned)f2fp8(v1.z) << 16) | ((unsigned)f2fp8(v1.w) << 24);
          *(uint2*)(C8 + (size_t)n * 128 + c8 * 8) = (uint2){lo, hi};
        }
      }
      // Ctil: 4 rounds; 16 lanes cover one 256B tiled chunk contiguously
      const int tile = nbase >> 4;
      #pragma unroll
      for (int rd = 0; rd < 4; ++rd) {
        int n16 = lane & 15, c2 = rd * 4 + (lane >> 4);
        float4 v0 = *(const float4*)&S[n16][c2 * 8];
        float4 v1 = *(const float4*)&S[n16][c2 * 8 + 4];
        int n = nbase + n16;
        if (n < n_nodes) {
          uint4 o;
          o.x = pack2(v0.x, v0.y); o.y = pack2(v0.z, v0.w);
          o.z = pack2(v1.x, v1.y); o.w = pack2(v1.z, v1.w);
          *(uint4*)(Ctil + ((size_t)(tile * 16 + c2)) * 128 + n16 * 8) = o;
        }
      }
    }
  }
}

// ---------- launch ----------
extern "C" void kernel_launch(void* const* d_in, const int* in_sizes, int n_in,
                              void* d_out, int out_size, void* d_ws, size_t ws_size,
                              hipStream_t stream) {
  const void* x_raw  = d_in[0];
  const int* idx_raw = (const int*)d_in[1];
  const void* W1l = d_in[2];
  const void* b1  = d_in[3];
  const void* W1r = d_in[4];
  const void* W2l = d_in[5];
  const void* b2  = d_in[6];
  const void* W2r = d_in[7];
  const int N = in_sizes[0] / 64;
  const int E = in_sizes[1] / 2;
  const int NP = (N + 127) & ~127;  // padded rows for tiled buffers
  const int NC = (E + CHUNK - 1) / CHUNK;
  const int NSCAN = NBUCKP * NC;
  const int NBs = (NSCAN + 2047) / 2048;
  const int NBUCK = (N + 127) >> 7;

  char* ws = (char*)d_ws;
  size_t off = 0;
  auto alloc = [&](size_t bytes) {
    char* p = ws + off;
    off = (off + bytes + 511) & ~((size_t)511);
    return p;
  };
  int* hdr        = (int*)alloc(512);
  int* H          = (int*)alloc((size_t)NSCAN * 4);
  int* O          = (int*)alloc((size_t)NSCAN * 4);
  int* blockSums  = (int*)alloc((size_t)NBs * 4);
  int* blockOffs  = (int*)alloc((size_t)NBs * 4);
  unsigned long long* ebuf = (unsigned long long*)alloc((size_t)E * 8);
  int* col        = (int*)alloc((size_t)E * 4);
  int* row_start  = (int*)alloc(((size_t)N + 1) * 4);
  float* deg_inv  = (float*)alloc((size_t)N * 4);
  unsigned short* Wf1 = (unsigned short*)alloc(32768);
  unsigned short* Wf2 = (unsigned short*)alloc(65536);
  float* b1_f     = (float*)alloc(512);
  float* b2_f     = (float*)alloc(512);
  unsigned char*  xc8     = (unsigned char*)alloc(((size_t)N + 1) * 64);        // +1 sentinel row
  unsigned short* xc_til  = (unsigned short*)alloc((size_t)NP * 64 * 2);
  unsigned short* agg1    = (unsigned short*)alloc((size_t)NP * 64 * 2);
  unsigned char*  hbuf8   = (unsigned char*)alloc(((size_t)N + 1) * 128);       // +1 sentinel row
  unsigned short* hbuf_til= (unsigned short*)alloc((size_t)NP * 128 * 2);
  unsigned short* agg2    = (unsigned short*)alloc((size_t)NP * 128 * 2);

  detect_kernel<<<1, 64, 0, stream>>>(x_raw, idx_raw, hdr,
                                      xc8 + (size_t)N * 64, hbuf8 + (size_t)N * 128);
  reorder_w_kernel<<<(6400 + 255) / 256, 256, 0, stream>>>(
      W1l, W1r, W2l, W2r, b1, b2, hdr, Wf1, Wf2, b1_f, b2_f);
  convert_x_kernel<<<(N * 64 + 255) / 256, 256, 0, stream>>>(x_raw, hdr, xc8, xc_til, N * 64);
  hist_chunks_kernel<<<NC, 256, 0, stream>>>(idx_raw, hdr, H, E, NC);
  gscan_sums_kernel<<<NBs, 256, 0, stream>>>(H, blockSums, NSCAN);
  gscan_offsets_kernel<<<1, 64, 0, stream>>>(blockSums, blockOffs, NBs);
  gscan_emit_kernel<<<NBs, 256, 0, stream>>>(H, blockOffs, O, NSCAN);
  scatter_kernel<<<NC, 256, 0, stream>>>(idx_raw, hdr, O, ebuf, E, NC);
  bucket_csr_kernel<<<NBUCK, 256, 0, stream>>>(ebuf, O, col, row_start, deg_inv, N, E, NC);
  gather1_kernel<<<(N + 7) / 8, 256, 0, stream>>>(xc8, row_start, col, deg_inv, agg1, N);
  gemm_mfma<64, 64, true, false><<<(N + 127) / 128, 256, 0, stream>>>(
      agg1, xc_til, Wf1, b1_f, hbuf8, hbuf_til, nullptr, hdr, N);
  gather2_kernel<<<(N + 3) / 4, 256, 0, stream>>>(hbuf8, row_start, col, deg_inv, agg2, N);
  gemm_mfma<128, 128, false, true><<<(N + 127) / 128, 256, 0, stream>>>(
      agg2, hbuf_til, Wf2, b2_f, nullptr, nullptr, d_out, hdr, N);
}